// Round 5
// baseline (1041.891 us; speedup 1.0000x reference)
//
#include <hip/hip_runtime.h>
#include <stdint.h>

#define BATCH 8192
#define DIM   1024            // elements per row; fp8 => also bytes per row
#define NTILE 64              // 8192 / 128 tiles per dimension
#define MAXB  292             // max tiles per XCD band
#define GRIDX (8 * MAXB)      // padded x-grid; blocks past band size exit

#define FSCALE 8.0f                          // pre-scale before fp8 quant
#define EXPF   (2.0f / (FSCALE * FSCALE))    // exp(2*dot) = exp(acc * EXPF)

typedef int   intx4   __attribute__((ext_vector_type(4)));
typedef int   intx8   __attribute__((ext_vector_type(8)));
typedef float floatx4 __attribute__((ext_vector_type(4)));

__device__ __forceinline__ void async_ld16(const void* g, void* l) {
    __builtin_amdgcn_global_load_lds(
        (__attribute__((address_space(1))) void*)(void*)g,
        (__attribute__((address_space(3))) void*)l,
        16, 0, 0);
}

// ------------- row L2-normalize: fp32 -> fp8 e4m3 (x FSCALE) -------------
__global__ __launch_bounds__(256) void norm_kernel(const float* __restrict__ text,
                                                   const float* __restrict__ image,
                                                   unsigned char* __restrict__ out) {
    const int fsel = blockIdx.y;
    const float* in = fsel ? image : text;
    unsigned char* o = out + (size_t)fsel * BATCH * DIM;
    const int row = blockIdx.x;
    const int t   = threadIdx.x;
    const float4* src = (const float4*)(in + (size_t)row * DIM);
    float4 v = src[t];
    float ss = v.x * v.x + v.y * v.y + v.z * v.z + v.w * v.w;
    #pragma unroll
    for (int m = 32; m >= 1; m >>= 1) ss += __shfl_xor(ss, m);
    __shared__ float red[4];
    if ((t & 63) == 0) red[t >> 6] = ss;
    __syncthreads();
    const float n2  = red[0] + red[1] + red[2] + red[3];
    const float inv = FSCALE / fmaxf(sqrtf(n2), 1e-12f);
    // pack 4 e4m3 bytes (gfx950: OCP e4m3fn), byte i = element t*4+i
    int p = __builtin_amdgcn_cvt_pk_fp8_f32(v.x * inv, v.y * inv, 0, false);
    p     = __builtin_amdgcn_cvt_pk_fp8_f32(v.z * inv, v.w * inv, p, true);
    ((int*)(o + (size_t)row * DIM))[t] = p;
}

// -------- fused symmetric sim GEMM (MX-fp8, unit scales) + exp + dual sum --------
// Upper-triangle tiles, XCD-banded schedule. BK=128 via
// mfma_scale_f32_16x16x128_f8f6f4 with all scales = 2^0 -> plain fp8 dot.
// __launch_bounds__(256,3): cap VGPR ~170 so 3 blocks/CU stay resident.
__global__ __launch_bounds__(256, 3) void sim_kernel(const unsigned char* __restrict__ F,
                                                     const int* __restrict__ label,
                                                     float* __restrict__ S) {
    // band tables: bj in [bs[x], be[x]); bn[x] = tiles in band
    const int bs[8] = {0, 23, 32, 40, 46, 51, 56, 60};
    const int be[8] = {23, 32, 40, 46, 51, 56, 60, 64};
    const int bn[8] = {276, 252, 292, 261, 245, 270, 234, 250};

    const int x = blockIdx.x & 7;       // XCD (round-robin dispatch heuristic)
    const int l = blockIdx.x >> 3;      // local index within band
    if (l >= bn[x]) return;             // padding block

    const int s = bs[x];
    const int w = be[x] - s;
    int bi, bj;
    const int nfull = s * w;
    if (l < nfull) {
        bi = l / w;
        bj = s + (l % w);
    } else {
        int l2 = l - nfull;
        int k = 0, width = w;
        while (l2 >= width) { l2 -= width; --width; ++k; }
        bi = s + k;
        bj = bi + l2;
    }
    const bool diag = (bi == bj);

    const int f = blockIdx.z;
    const unsigned char* A = F + (size_t)f * BATCH * DIM;
    float* SR = S + (size_t)f * 2 * BATCH;
    float* SN = SR + BATCH;

    const int rowTile = bi * 128;
    const int colTile = bj * 128;

    // 128 rows x 128 K-bytes per tile, 16-B chunk swizzle: chunk c of row r
    // stored at slot c ^ (r&7)  -> per-8-lane-perfect b128 frag reads.
    __shared__ __align__(16) unsigned char As[128 * 128];
    __shared__ __align__(16) unsigned char Bs[128 * 128];

    const int tid  = threadIdx.x;
    const int lane = tid & 63;
    const int wave = tid >> 6;
    const int wm   = wave >> 1;        // 2x2 wave grid over the 128x128 tile
    const int wn   = wave & 1;
    const int quad = lane >> 4;
    const int cl   = lane & 15;

    // staging: issue t covers rows wave*32 + t*8 .. +8; lane -> row lane>>3,
    // LDS slot lane&7 (HW: dest = base + lane*16), global chunk = slot ^ (row&7)
    const int sRowOff = lane >> 3;            // 0..7
    const int chunk   = (lane & 7) ^ sRowOff; // (row&7) == sRowOff
    const unsigned char* gA = A + (size_t)(rowTile + wave * 32 + sRowOff) * DIM + chunk * 16;
    const unsigned char* gB = A + (size_t)(colTile + wave * 32 + sRowOff) * DIM + chunk * 16;
    unsigned char* lA = As + wave * 32 * 128 + lane * 16;
    unsigned char* lB = Bs + wave * 32 * 128 + lane * 16;

    floatx4 acc[4][4];
    const floatx4 z4 = {0.f, 0.f, 0.f, 0.f};
    #pragma unroll
    for (int mi = 0; mi < 4; ++mi)
        #pragma unroll
        for (int ni = 0; ni < 4; ++ni) acc[mi][ni] = z4;

    // frag read slots (un-swizzle): lane reads 16-B chunks 2q and 2q+1 of its row
    const int h  = cl & 7;
    const int s0 = ((2 * quad) ^ h) * 16;
    const int s1 = ((2 * quad + 1) ^ h) * 16;
    const unsigned char* aRow = As + (size_t)(wm * 64 + cl) * 128;
    const unsigned char* bRow = Bs + (size_t)(wn * 64 + cl) * 128;

    for (int k0 = 0; k0 < DIM; k0 += 128) {
        __syncthreads();                 // all waves done reading previous tile
        #pragma unroll
        for (int t = 0; t < 4; ++t) {
            async_ld16(gA + (size_t)t * 8 * DIM, lA + t * 1024);
            async_ld16(gB + (size_t)t * 8 * DIM, lB + t * 1024);
        }
        gA += 128; gB += 128;
        __syncthreads();                 // vmcnt drain + all data visible

        intx8 af[4], bf[4];
        #pragma unroll
        for (int mi = 0; mi < 4; ++mi) {
            const unsigned char* r = aRow + mi * 16 * 128;
            intx4 lo = *(const intx4*)(r + s0);
            intx4 hi = *(const intx4*)(r + s1);
            af[mi] = __builtin_shufflevector(lo, hi, 0, 1, 2, 3, 4, 5, 6, 7);
        }
        #pragma unroll
        for (int ni = 0; ni < 4; ++ni) {
            const unsigned char* r = bRow + ni * 16 * 128;
            intx4 lo = *(const intx4*)(r + s0);
            intx4 hi = *(const intx4*)(r + s1);
            bf[ni] = __builtin_shufflevector(lo, hi, 0, 1, 2, 3, 4, 5, 6, 7);
        }
        #pragma unroll
        for (int mi = 0; mi < 4; ++mi)
            #pragma unroll
            for (int ni = 0; ni < 4; ++ni)
                acc[mi][ni] = __builtin_amdgcn_mfma_scale_f32_16x16x128_f8f6f4(
                    af[mi], bf[ni], acc[mi][ni],
                    0, 0,                     // cbsz=fp8(e4m3), blgp=fp8(e4m3)
                    0, 0x7F7F7F7F,            // scale_a opsel, scale_a = 2^0
                    0, 0x7F7F7F7F);           // scale_b opsel, scale_b = 2^0
    }

    // ---- epilogue: e = exp(acc * 2/FSCALE^2), eye mask, dual row/col sums ----
    int   colg[4];
    float wRc[4];                        // col label weight (row-part bucket)
    #pragma unroll
    for (int ni = 0; ni < 4; ++ni) {
        colg[ni] = colTile + wn * 64 + ni * 16 + cl;
        wRc[ni]  = (label[colg[ni]] != 0) ? 1.0f : 0.0f;
    }

    float colR[4] = {0.f, 0.f, 0.f, 0.f};
    float colN[4] = {0.f, 0.f, 0.f, 0.f};

    #pragma unroll
    for (int mi = 0; mi < 4; ++mi) {
        const int rowBase = rowTile + wm * 64 + mi * 16 + quad * 4;   // C/D: row=quad*4+reg
        #pragma unroll
        for (int r = 0; r < 4; ++r) {
            const int rowg = rowBase + r;
            const float wRr = (label[rowg] != 0) ? 1.0f : 0.0f;
            float pR = 0.f, pN = 0.f;
            #pragma unroll
            for (int ni = 0; ni < 4; ++ni) {
                float c = acc[mi][ni][r];
                float e = __expf(c * EXPF);
                if (diag) e = (rowg == colg[ni]) ? 0.0f : e;      // eye mask
                pR += wRc[ni] * e;
                pN += (1.0f - wRc[ni]) * e;
                colR[ni] += wRr * e;
                colN[ni] += (1.0f - wRr) * e;
            }
            #pragma unroll
            for (int m = 1; m < 16; m <<= 1) {
                pR += __shfl_xor(pR, m);
                pN += __shfl_xor(pN, m);
            }
            if (cl == 0) {
                atomicAdd(&SR[rowg], pR);
                atomicAdd(&SN[rowg], pN);
            }
        }
    }

    if (!diag) {
        #pragma unroll
        for (int ni = 0; ni < 4; ++ni) {
            float cR = colR[ni], cN = colN[ni];
            cR += __shfl_xor(cR, 16); cN += __shfl_xor(cN, 16);
            cR += __shfl_xor(cR, 32); cN += __shfl_xor(cN, 32);
            if (quad == 0) {
                atomicAdd(&SR[colg[ni]], cR);
                atomicAdd(&SN[colg[ni]], cN);
            }
        }
    }
}

// ---------------- final per-row loss + global reduce ----------------
__global__ __launch_bounds__(256) void loss_kernel(const float* __restrict__ S,
                                                   const int* __restrict__ label,
                                                   float* __restrict__ out) {
    const int i = blockIdx.x * 256 + threadIdx.x;   // 0..8191
    const int lab = label[i];
    float t = 0.f;
    #pragma unroll
    for (int f = 0; f < 2; ++f) {
        const float* SR = S + (size_t)f * 2 * BATCH;
        const float* SN = SR + BATCH;
        const float own = lab ? SR[i] : SN[i];
        const float oth = lab ? SN[i] : SR[i];
        t += -logf(own / (own + oth) + 1e-8f);
    }
    t *= (1.0f / 4096.0f);
    #pragma unroll
    for (int m = 32; m >= 1; m >>= 1) t += __shfl_xor(t, m);
    __shared__ float red[4];
    if ((threadIdx.x & 63) == 0) red[threadIdx.x >> 6] = t;
    __syncthreads();
    if (threadIdx.x == 0) atomicAdd(out, red[0] + red[1] + red[2] + red[3]);
}

extern "C" void kernel_launch(void* const* d_in, const int* in_sizes, int n_in,
                              void* d_out, int out_size, void* d_ws, size_t ws_size,
                              hipStream_t stream) {
    const float* text  = (const float*)d_in[0];
    const float* image = (const float*)d_in[1];
    const int*   label = (const int*)d_in[2];
    float* out = (float*)d_out;

    // workspace: Fn[2][8192][1024] fp8 (16 MB), then S[2][2][8192] f32
    unsigned char* Fn = (unsigned char*)d_ws;
    float* S = (float*)((char*)d_ws + (size_t)2 * BATCH * DIM);

    hipMemsetAsync(S, 0, (size_t)2 * 2 * BATCH * sizeof(float), stream);
    hipMemsetAsync(out, 0, sizeof(float), stream);

    dim3 ngrid(BATCH, 2);
    norm_kernel<<<ngrid, 256, 0, stream>>>(text, image, Fn);

    dim3 grid(GRIDX, 1, 2);
    sim_kernel<<<grid, 256, 0, stream>>>(Fn, label, S);

    loss_kernel<<<BATCH / 256, 256, 0, stream>>>(S, label, out);
}

// Round 6
// 360.420 us; speedup vs baseline: 2.8908x; 2.8908x over previous
//
#include <hip/hip_runtime.h>
#include <stdint.h>

#define BATCH 8192
#define DIM   1024            // elements per row; fp8 => also bytes per row
#define NTILE 64              // 8192 / 128 tiles per dimension
#define MAXB  292             // max tiles per XCD band
#define GRIDX (8 * MAXB)      // padded x-grid; blocks past band size exit
#define TILEB (128 * 128)     // LDS bytes per tile buffer

#define FSCALE 8.0f                          // pre-scale before fp8 quant
#define EXPF   (2.0f / (FSCALE * FSCALE))    // exp(2*dot) = exp(acc * EXPF)

typedef int   intx4   __attribute__((ext_vector_type(4)));
typedef int   intx8   __attribute__((ext_vector_type(8)));
typedef float floatx4 __attribute__((ext_vector_type(4)));

__device__ __forceinline__ void async_ld16(const void* g, void* l) {
    __builtin_amdgcn_global_load_lds(
        (__attribute__((address_space(1))) void*)(void*)g,
        (__attribute__((address_space(3))) void*)l,
        16, 0, 0);
}

// ------------- row L2-normalize: fp32 -> fp8 e4m3 (x FSCALE) -------------
__global__ __launch_bounds__(256) void norm_kernel(const float* __restrict__ text,
                                                   const float* __restrict__ image,
                                                   unsigned char* __restrict__ out) {
    const int fsel = blockIdx.y;
    const float* in = fsel ? image : text;
    unsigned char* o = out + (size_t)fsel * BATCH * DIM;
    const int row = blockIdx.x;
    const int t   = threadIdx.x;
    const float4* src = (const float4*)(in + (size_t)row * DIM);
    float4 v = src[t];
    float ss = v.x * v.x + v.y * v.y + v.z * v.z + v.w * v.w;
    #pragma unroll
    for (int m = 32; m >= 1; m >>= 1) ss += __shfl_xor(ss, m);
    __shared__ float red[4];
    if ((t & 63) == 0) red[t >> 6] = ss;
    __syncthreads();
    const float n2  = red[0] + red[1] + red[2] + red[3];
    const float inv = FSCALE / fmaxf(sqrtf(n2), 1e-12f);
    // pack 4 e4m3 bytes (gfx950: OCP e4m3fn), byte i = element t*4+i
    int p = __builtin_amdgcn_cvt_pk_fp8_f32(v.x * inv, v.y * inv, 0, false);
    p     = __builtin_amdgcn_cvt_pk_fp8_f32(v.z * inv, v.w * inv, p, true);
    ((int*)(o + (size_t)row * DIM))[t] = p;
}

// -------- fused symmetric sim GEMM (MX-fp8, unit scales) + exp + dual sum --------
// Upper-triangle tiles, XCD-banded schedule. BK=128 via
// mfma_scale_f32_16x16x128_f8f6f4 with all scales = 2^0 -> plain fp8 dot.
// Producer-consumer pipelined K-loop: double-buffered LDS, ONE barrier/iter;
// next tile's global_load_lds issued into the idle buffer BEFORE frag reads,
// so the vmcnt drain at the next barrier lands after ~550 cyc of MFMA issue.
// NOTE: do NOT use the 2nd __launch_bounds__ arg here (r5: forced 84 VGPR,
// spilled accs in the K-loop, 1.45 GB scratch writes, 3.7x regression).
__global__ __launch_bounds__(256) void sim_kernel(const unsigned char* __restrict__ F,
                                                  const int* __restrict__ label,
                                                  float* __restrict__ S) {
    // band tables: bj in [bs[x], be[x]); bn[x] = tiles in band
    const int bs[8] = {0, 23, 32, 40, 46, 51, 56, 60};
    const int be[8] = {23, 32, 40, 46, 51, 56, 60, 64};
    const int bn[8] = {276, 252, 292, 261, 245, 270, 234, 250};

    const int x = blockIdx.x & 7;       // XCD (round-robin dispatch heuristic)
    const int l = blockIdx.x >> 3;      // local index within band
    if (l >= bn[x]) return;             // padding block

    const int s = bs[x];
    const int w = be[x] - s;
    int bi, bj;
    const int nfull = s * w;
    if (l < nfull) {
        bi = l / w;
        bj = s + (l % w);
    } else {
        int l2 = l - nfull;
        int k = 0, width = w;
        while (l2 >= width) { l2 -= width; --width; ++k; }
        bi = s + k;
        bj = bi + l2;
    }
    const bool diag = (bi == bj);

    const int f = blockIdx.z;
    const unsigned char* A = F + (size_t)f * BATCH * DIM;
    float* SR = S + (size_t)f * 2 * BATCH;
    float* SN = SR + BATCH;

    const int rowTile = bi * 128;
    const int colTile = bj * 128;

    // double-buffered 128x128-byte tiles; 16-B chunk swizzle: chunk c of row r
    // stored at slot c ^ (r&7)  -> per-8-lane-perfect b128 frag reads.
    __shared__ __align__(16) unsigned char As[2 * TILEB];
    __shared__ __align__(16) unsigned char Bs[2 * TILEB];

    const int tid  = threadIdx.x;
    const int lane = tid & 63;
    const int wave = tid >> 6;
    const int wm   = wave >> 1;        // 2x2 wave grid over the 128x128 tile
    const int wn   = wave & 1;
    const int quad = lane >> 4;
    const int cl   = lane & 15;

    // staging: issue t covers rows wave*32 + t*8 .. +8; lane -> row lane>>3,
    // LDS slot lane&7 (HW: dest = base + lane*16), global chunk = slot ^ (row&7)
    const int sRowOff = lane >> 3;            // 0..7
    const int chunk   = (lane & 7) ^ sRowOff; // (row&7) == sRowOff
    const unsigned char* gA = A + (size_t)(rowTile + wave * 32 + sRowOff) * DIM + chunk * 16;
    const unsigned char* gB = A + (size_t)(colTile + wave * 32 + sRowOff) * DIM + chunk * 16;
    const int lOff = wave * 32 * 128 + lane * 16;   // within a tile buffer

    floatx4 acc[4][4];
    const floatx4 z4 = {0.f, 0.f, 0.f, 0.f};
    #pragma unroll
    for (int mi = 0; mi < 4; ++mi)
        #pragma unroll
        for (int ni = 0; ni < 4; ++ni) acc[mi][ni] = z4;

    // frag read slots (un-swizzle): lane reads 16-B chunks 2q and 2q+1 of its row
    const int h  = cl & 15 & 7;
    const int s0 = ((2 * quad) ^ h) * 16;
    const int s1 = ((2 * quad + 1) ^ h) * 16;
    const int aRowOff = (wm * 64 + cl) * 128;       // within a tile buffer
    const int bRowOff = (wn * 64 + cl) * 128;

    // preload tile 0 into buffer 0
    #pragma unroll
    for (int t = 0; t < 4; ++t) {
        async_ld16(gA + (size_t)t * 8 * DIM, As + lOff + t * 1024);
        async_ld16(gB + (size_t)t * 8 * DIM, Bs + lOff + t * 1024);
    }
    gA += 128; gB += 128;

    for (int k0 = 0; k0 < DIM; k0 += 128) {
        const int cur = (k0 >> 7) & 1;
        __syncthreads();   // drains own vmcnt -> buffer `cur` fully populated

        // issue next tile into the idle buffer BEFORE consuming current one:
        // overwrites buffer cur^1, which every wave finished reading before
        // the barrier above (compiler drains lgkm before s_barrier).
        if (k0 + 128 < DIM) {
            const int nxt = cur ^ 1;
            #pragma unroll
            for (int t = 0; t < 4; ++t) {
                async_ld16(gA + (size_t)t * 8 * DIM, As + nxt * TILEB + lOff + t * 1024);
                async_ld16(gB + (size_t)t * 8 * DIM, Bs + nxt * TILEB + lOff + t * 1024);
            }
            gA += 128; gB += 128;
        }

        const unsigned char* aRow = As + cur * TILEB + aRowOff;
        const unsigned char* bRow = Bs + cur * TILEB + bRowOff;

        intx8 af[4];
        #pragma unroll
        for (int mi = 0; mi < 4; ++mi) {
            const unsigned char* r = aRow + mi * 16 * 128;
            intx4 lo = *(const intx4*)(r + s0);
            intx4 hi = *(const intx4*)(r + s1);
            af[mi] = __builtin_shufflevector(lo, hi, 0, 1, 2, 3, 4, 5, 6, 7);
        }
        #pragma unroll
        for (int ni = 0; ni < 4; ++ni) {
            const unsigned char* r = bRow + ni * 16 * 128;
            intx4 lo = *(const intx4*)(r + s0);
            intx4 hi = *(const intx4*)(r + s1);
            intx8 bfv = __builtin_shufflevector(lo, hi, 0, 1, 2, 3, 4, 5, 6, 7);
            #pragma unroll
            for (int mi = 0; mi < 4; ++mi)
                acc[mi][ni] = __builtin_amdgcn_mfma_scale_f32_16x16x128_f8f6f4(
                    af[mi], bfv, acc[mi][ni],
                    0, 0,                     // cbsz=fp8(e4m3), blgp=fp8(e4m3)
                    0, 0x7F7F7F7F,            // scale_a opsel, scale_a = 2^0
                    0, 0x7F7F7F7F);           // scale_b opsel, scale_b = 2^0
        }
    }

    // ---- epilogue: e = exp(acc * 2/FSCALE^2), eye mask, dual row/col sums ----
    int   colg[4];
    float wRc[4];                        // col label weight (row-part bucket)
    #pragma unroll
    for (int ni = 0; ni < 4; ++ni) {
        colg[ni] = colTile + wn * 64 + ni * 16 + cl;
        wRc[ni]  = (label[colg[ni]] != 0) ? 1.0f : 0.0f;
    }

    float colR[4] = {0.f, 0.f, 0.f, 0.f};
    float colN[4] = {0.f, 0.f, 0.f, 0.f};

    #pragma unroll
    for (int mi = 0; mi < 4; ++mi) {
        const int rowBase = rowTile + wm * 64 + mi * 16 + quad * 4;   // C/D: row=quad*4+reg
        #pragma unroll
        for (int r = 0; r < 4; ++r) {
            const int rowg = rowBase + r;
            const float wRr = (label[rowg] != 0) ? 1.0f : 0.0f;
            float pR = 0.f, pN = 0.f;
            #pragma unroll
            for (int ni = 0; ni < 4; ++ni) {
                float c = acc[mi][ni][r];
                float e = __expf(c * EXPF);
                if (diag) e = (rowg == colg[ni]) ? 0.0f : e;      // eye mask
                pR += wRc[ni] * e;
                pN += (1.0f - wRc[ni]) * e;
                colR[ni] += wRr * e;
                colN[ni] += (1.0f - wRr) * e;
            }
            #pragma unroll
            for (int m = 1; m < 16; m <<= 1) {
                pR += __shfl_xor(pR, m);
                pN += __shfl_xor(pN, m);
            }
            if (cl == 0) {
                atomicAdd(&SR[rowg], pR);
                atomicAdd(&SN[rowg], pN);
            }
        }
    }

    if (!diag) {
        #pragma unroll
        for (int ni = 0; ni < 4; ++ni) {
            float cR = colR[ni], cN = colN[ni];
            cR += __shfl_xor(cR, 16); cN += __shfl_xor(cN, 16);
            cR += __shfl_xor(cR, 32); cN += __shfl_xor(cN, 32);
            if (quad == 0) {
                atomicAdd(&SR[colg[ni]], cR);
                atomicAdd(&SN[colg[ni]], cN);
            }
        }
    }
}

// ---------------- final per-row loss + global reduce ----------------
__global__ __launch_bounds__(256) void loss_kernel(const float* __restrict__ S,
                                                   const int* __restrict__ label,
                                                   float* __restrict__ out) {
    const int i = blockIdx.x * 256 + threadIdx.x;   // 0..8191
    const int lab = label[i];
    float t = 0.f;
    #pragma unroll
    for (int f = 0; f < 2; ++f) {
        const float* SR = S + (size_t)f * 2 * BATCH;
        const float* SN = SR + BATCH;
        const float own = lab ? SR[i] : SN[i];
        const float oth = lab ? SN[i] : SR[i];
        t += -logf(own / (own + oth) + 1e-8f);
    }
    t *= (1.0f / 4096.0f);
    #pragma unroll
    for (int m = 32; m >= 1; m >>= 1) t += __shfl_xor(t, m);
    __shared__ float red[4];
    if ((threadIdx.x & 63) == 0) red[threadIdx.x >> 6] = t;
    __syncthreads();
    if (threadIdx.x == 0) atomicAdd(out, red[0] + red[1] + red[2] + red[3]);
}

extern "C" void kernel_launch(void* const* d_in, const int* in_sizes, int n_in,
                              void* d_out, int out_size, void* d_ws, size_t ws_size,
                              hipStream_t stream) {
    const float* text  = (const float*)d_in[0];
    const float* image = (const float*)d_in[1];
    const int*   label = (const int*)d_in[2];
    float* out = (float*)d_out;

    // workspace: Fn[2][8192][1024] fp8 (16 MB), then S[2][2][8192] f32
    unsigned char* Fn = (unsigned char*)d_ws;
    float* S = (float*)((char*)d_ws + (size_t)2 * BATCH * DIM);

    hipMemsetAsync(S, 0, (size_t)2 * 2 * BATCH * sizeof(float), stream);
    hipMemsetAsync(out, 0, sizeof(float), stream);

    dim3 ngrid(BATCH, 2);
    norm_kernel<<<ngrid, 256, 0, stream>>>(text, image, Fn);

    dim3 grid(GRIDX, 1, 2);
    sim_kernel<<<grid, 256, 0, stream>>>(Fn, label, S);

    loss_kernel<<<BATCH / 256, 256, 0, stream>>>(S, label, out);
}